// Round 1
// baseline (1272.267 us; speedup 1.0000x reference)
//
#include <hip/hip_runtime.h>
#include <cstdint>
#include <cstddef>

// ---------------------------------------------------------------------------
// SAGE GNN forward: 5x SAGEConv(mean) + relu, linear head + softmax.
// Baseline: all f32. CSR built per launch (deterministic up to f32 sum order).
// ---------------------------------------------------------------------------

static inline int idiv_up(int a, int b) { return (a + b - 1) / b; }

__global__ void k_zero_int(int* __restrict__ p, int n) {
  int i = blockIdx.x * blockDim.x + threadIdx.x;
  if (i < n) p[i] = 0;
}

__global__ void k_count_deg(const int* __restrict__ dst, int* __restrict__ deg, int E) {
  int e = blockIdx.x * blockDim.x + threadIdx.x;
  if (e < E) atomicAdd(deg + dst[e], 1);
}

#define SCAN_B 1024
// Single-block exclusive scan over deg -> row_off; also cursor copy + deg_inv.
__global__ __launch_bounds__(SCAN_B)
void k_scan(const int* __restrict__ deg, int* __restrict__ row_off, int* __restrict__ cursor,
            float* __restrict__ deg_inv, int n) {
  __shared__ int sh[SCAN_B];
  __shared__ int carry_sh;
  const int tid = threadIdx.x;
  if (tid == 0) carry_sh = 0;
  __syncthreads();
  for (int base = 0; base < n; base += SCAN_B) {
    const int i = base + tid;
    const int v = (i < n) ? deg[i] : 0;
    sh[tid] = v;
    __syncthreads();
    for (int off = 1; off < SCAN_B; off <<= 1) {
      int t = (tid >= off) ? sh[tid - off] : 0;
      __syncthreads();
      sh[tid] += t;
      __syncthreads();
    }
    const int incl = sh[tid];
    const int c = carry_sh;
    if (i < n) {
      const int ro = c + incl - v;
      row_off[i] = ro;
      cursor[i] = ro;
      deg_inv[i] = 1.0f / (float)((v > 1) ? v : 1);
    }
    __syncthreads();
    if (tid == SCAN_B - 1) carry_sh = c + incl;
    __syncthreads();
  }
  if (tid == 0) row_off[n] = carry_sh;
}

__global__ void k_fill_csr(const int* __restrict__ src, const int* __restrict__ dst,
                           int* __restrict__ cursor, int* __restrict__ esrc, int E) {
  int e = blockIdx.x * blockDim.x + threadIdx.x;
  if (e < E) {
    int d = dst[e];
    int p = atomicAdd(cursor + d, 1);
    esrc[p] = src[e];
  }
}

// One block (K threads) per node: sum h[src] rows over incoming edges, * deg_inv.
template <int K>
__global__ void k_aggregate(const float* __restrict__ h, const int* __restrict__ row_off,
                            const int* __restrict__ esrc, const float* __restrict__ deg_inv,
                            float* __restrict__ agg) {
  const int n = blockIdx.x;
  const int t = threadIdx.x;
  const int s0 = row_off[n], s1 = row_off[n + 1];
  float sum = 0.f;
  for (int i = s0; i < s1; ++i) {
    const int s = esrc[i];
    sum += h[(size_t)s * K + t];
  }
  agg[(size_t)n * K + t] = sum * deg_inv[n];
}

// C[n,o] = relu( sum_k A0[n,k]*B0[o,k] + sum_k A1[n,k]*B1[o,k] + bias[o] )
// BM=BN=64, BK=16, 256 threads, 4x4 microtile. K % 16 == 0, O % 64 == 0.
__global__ __launch_bounds__(256)
void k_gemm_bias_relu(const float* __restrict__ A0, const float* __restrict__ B0,
                      const float* __restrict__ A1, const float* __restrict__ B1,
                      const float* __restrict__ bias, float* __restrict__ C,
                      int Nn, int K, int O) {
  __shared__ float As[16][64];
  __shared__ float Bs[16][64];
  const int bm = blockIdx.x * 64;
  const int bn = blockIdx.y * 64;
  const int tid = threadIdx.x;
  const int tx = tid & 15;        // output-col group
  const int ty = tid >> 4;        // output-row group
  const int lr = tid >> 2;        // loader row 0..63
  const int lk = (tid & 3) << 2;  // loader k offset (float4)
  float acc[4][4] = {{0.f}};
  for (int phase = 0; phase < 2; ++phase) {
    const float* __restrict__ A = phase ? A1 : A0;
    const float* __restrict__ B = phase ? B1 : B0;
    for (int kt = 0; kt < K; kt += 16) {
      float4 av = make_float4(0.f, 0.f, 0.f, 0.f);
      const int ar = bm + lr;
      if (ar < Nn) av = *(const float4*)(A + (size_t)ar * K + (kt + lk));
      const float4 bv = *(const float4*)(B + (size_t)(bn + lr) * K + (kt + lk));
      __syncthreads();
      As[lk + 0][lr] = av.x; As[lk + 1][lr] = av.y; As[lk + 2][lr] = av.z; As[lk + 3][lr] = av.w;
      Bs[lk + 0][lr] = bv.x; Bs[lk + 1][lr] = bv.y; Bs[lk + 2][lr] = bv.z; Bs[lk + 3][lr] = bv.w;
      __syncthreads();
#pragma unroll
      for (int kk = 0; kk < 16; ++kk) {
        const float4 a = *(const float4*)&As[kk][ty << 2];
        const float4 b = *(const float4*)&Bs[kk][tx << 2];
        acc[0][0] = fmaf(a.x, b.x, acc[0][0]); acc[0][1] = fmaf(a.x, b.y, acc[0][1]);
        acc[0][2] = fmaf(a.x, b.z, acc[0][2]); acc[0][3] = fmaf(a.x, b.w, acc[0][3]);
        acc[1][0] = fmaf(a.y, b.x, acc[1][0]); acc[1][1] = fmaf(a.y, b.y, acc[1][1]);
        acc[1][2] = fmaf(a.y, b.z, acc[1][2]); acc[1][3] = fmaf(a.y, b.w, acc[1][3]);
        acc[2][0] = fmaf(a.z, b.x, acc[2][0]); acc[2][1] = fmaf(a.z, b.y, acc[2][1]);
        acc[2][2] = fmaf(a.z, b.z, acc[2][2]); acc[2][3] = fmaf(a.z, b.w, acc[2][3]);
        acc[3][0] = fmaf(a.w, b.x, acc[3][0]); acc[3][1] = fmaf(a.w, b.y, acc[3][1]);
        acc[3][2] = fmaf(a.w, b.z, acc[3][2]); acc[3][3] = fmaf(a.w, b.w, acc[3][3]);
      }
    }
  }
  const float4 bb = *(const float4*)(bias + bn + (tx << 2));
#pragma unroll
  for (int i = 0; i < 4; ++i) {
    const int row = bm + (ty << 2) + i;
    if (row < Nn) {
      float4 v;
      v.x = fmaxf(acc[i][0] + bb.x, 0.f);
      v.y = fmaxf(acc[i][1] + bb.y, 0.f);
      v.z = fmaxf(acc[i][2] + bb.z, 0.f);
      v.w = fmaxf(acc[i][3] + bb.w, 0.f);
      *(float4*)(C + (size_t)row * O + bn + (tx << 2)) = v;
    }
  }
}

// logits = h @ Wout.T + bout (K=512, O=4), then softmax. One wave per node.
__global__ __launch_bounds__(64)
void k_out_softmax(const float* __restrict__ h, const float* __restrict__ W,
                   const float* __restrict__ b, float* __restrict__ out) {
  const int n = blockIdx.x;
  const int lane = threadIdx.x;
  const float* hr = h + (size_t)n * 512;
  float a0 = 0.f, a1 = 0.f, a2 = 0.f, a3 = 0.f;
  for (int k = lane; k < 512; k += 64) {
    const float hv = hr[k];
    a0 = fmaf(hv, W[k], a0);
    a1 = fmaf(hv, W[512 + k], a1);
    a2 = fmaf(hv, W[1024 + k], a2);
    a3 = fmaf(hv, W[1536 + k], a3);
  }
#pragma unroll
  for (int off = 32; off > 0; off >>= 1) {
    a0 += __shfl_down(a0, off);
    a1 += __shfl_down(a1, off);
    a2 += __shfl_down(a2, off);
    a3 += __shfl_down(a3, off);
  }
  if (lane == 0) {
    const float l0 = a0 + b[0], l1 = a1 + b[1], l2 = a2 + b[2], l3 = a3 + b[3];
    const float m = fmaxf(fmaxf(l0, l1), fmaxf(l2, l3));
    const float e0 = expf(l0 - m), e1 = expf(l1 - m), e2 = expf(l2 - m), e3 = expf(l3 - m);
    const float inv = 1.0f / (e0 + e1 + e2 + e3);
    float4 r;
    r.x = e0 * inv; r.y = e1 * inv; r.z = e2 * inv; r.w = e3 * inv;
    *(float4*)(out + (size_t)n * 4) = r;
  }
}

extern "C" void kernel_launch(void* const* d_in, const int* in_sizes, int n_in,
                              void* d_out, int out_size, void* d_ws, size_t ws_size,
                              hipStream_t stream) {
  const float* x = (const float*)d_in[0];
  const float* Wl[5] = {(const float*)d_in[1], (const float*)d_in[4], (const float*)d_in[7],
                        (const float*)d_in[10], (const float*)d_in[13]};
  const float* bl[5] = {(const float*)d_in[2], (const float*)d_in[5], (const float*)d_in[8],
                        (const float*)d_in[11], (const float*)d_in[14]};
  const float* Wr[5] = {(const float*)d_in[3], (const float*)d_in[6], (const float*)d_in[9],
                        (const float*)d_in[12], (const float*)d_in[15]};
  const float* Wout = (const float*)d_in[16];
  const float* bout = (const float*)d_in[17];
  const int* eidx = (const int*)d_in[18];

  const int N = in_sizes[0] / 128;
  const int E = in_sizes[18] / 2;
  const int* srcI = eidx;
  const int* dstI = eidx + E;

  // workspace carve-out (256B aligned)
  char* ws = (char*)d_ws;
  size_t p = 0;
  auto alloc = [&](size_t bytes) { size_t r = p; p += (bytes + 255) & ~(size_t)255; return r; };
  int*   deg     = (int*)(ws + alloc((size_t)N * 4));
  int*   row_off = (int*)(ws + alloc((size_t)(N + 1) * 4));
  int*   cursor  = (int*)(ws + alloc((size_t)N * 4));
  float* deg_inv = (float*)(ws + alloc((size_t)N * 4));
  int*   esrc    = (int*)(ws + alloc((size_t)E * 4));
  float* bufA    = (float*)(ws + alloc((size_t)N * 512 * 4)); // layers 0,2,4 outputs
  float* bufB    = (float*)(ws + alloc((size_t)N * 256 * 4)); // layers 1,3 outputs
  float* agg     = (float*)(ws + alloc((size_t)N * 256 * 4));
  (void)ws_size; (void)n_in; (void)out_size;

  // ---- CSR build (per launch; deterministic work, bucket order may vary) ----
  k_zero_int<<<idiv_up(N, 256), 256, 0, stream>>>(deg, N);
  k_count_deg<<<idiv_up(E, 256), 256, 0, stream>>>(dstI, deg, E);
  k_scan<<<1, SCAN_B, 0, stream>>>(deg, row_off, cursor, deg_inv, N);
  k_fill_csr<<<idiv_up(E, 256), 256, 0, stream>>>(srcI, dstI, cursor, esrc, E);

  const int Kd[5] = {128, 128, 64, 128, 256};
  const int Od[5] = {128, 64, 128, 256, 512};
  float* houts[5] = {bufA, bufB, bufA, bufB, bufA};

  const float* hin = x;
  for (int l = 0; l < 5; ++l) {
    const int K = Kd[l], O = Od[l];
    if (K == 64)
      k_aggregate<64><<<N, 64, 0, stream>>>(hin, row_off, esrc, deg_inv, agg);
    else if (K == 128)
      k_aggregate<128><<<N, 128, 0, stream>>>(hin, row_off, esrc, deg_inv, agg);
    else
      k_aggregate<256><<<N, 256, 0, stream>>>(hin, row_off, esrc, deg_inv, agg);

    float* hout = houts[l];
    k_gemm_bias_relu<<<dim3(idiv_up(N, 64), O / 64), 256, 0, stream>>>(
        agg, Wl[l], hin, Wr[l], bl[l], hout, N, K, O);
    hin = hout;
  }
  k_out_softmax<<<N, 64, 0, stream>>>(hin, Wout, bout, (float*)d_out);
}

// Round 2
// 875.075 us; speedup vs baseline: 1.4539x; 1.4539x over previous
//
#include <hip/hip_runtime.h>
#include <hip/hip_bf16.h>
#include <cstdint>
#include <cstddef>

// ---------------------------------------------------------------------------
// SAGE GNN forward, bf16 edition:
//   - hidden state + agg in bf16, MFMA 16x16x32 bf16 GEMMs (f32 accum)
//   - operands loaded directly from global (L2/L3-resident), no LDS
//   - CSR built per launch; gather in bf16 (halved traffic)
// ---------------------------------------------------------------------------

typedef short bf16x8 __attribute__((ext_vector_type(8)));   // 8 bf16 = 4 VGPRs
typedef float f32x4 __attribute__((ext_vector_type(4)));

static inline int idiv_up(int a, int b) { return (a + b - 1) / b; }

static __device__ __forceinline__ float bf2f(unsigned short u) {
  union { unsigned int i; float f; } v; v.i = ((unsigned int)u) << 16; return v.f;
}
static __device__ __forceinline__ unsigned short f2bf(float f) {
  union { float f; unsigned int i; } v; v.f = f;
  return (unsigned short)((v.i + 0x7FFFu + ((v.i >> 16) & 1u)) >> 16);  // RNE
}

// ---------------- CSR build ----------------
__global__ void k_zero_int(int* __restrict__ p, int n) {
  int i = blockIdx.x * blockDim.x + threadIdx.x;
  if (i < n) p[i] = 0;
}

__global__ void k_count_deg(const int* __restrict__ dst, int* __restrict__ deg, int E) {
  int e = blockIdx.x * blockDim.x + threadIdx.x;
  if (e < E) atomicAdd(deg + dst[e], 1);
}

#define SCAN_B 1024
__global__ __launch_bounds__(SCAN_B)
void k_scan(const int* __restrict__ deg, int* __restrict__ row_off, int* __restrict__ cursor,
            float* __restrict__ deg_inv, int n) {
  __shared__ int sh[SCAN_B];
  __shared__ int carry_sh;
  const int tid = threadIdx.x;
  if (tid == 0) carry_sh = 0;
  __syncthreads();
  for (int base = 0; base < n; base += SCAN_B) {
    const int i = base + tid;
    const int v = (i < n) ? deg[i] : 0;
    sh[tid] = v;
    __syncthreads();
    for (int off = 1; off < SCAN_B; off <<= 1) {
      int t = (tid >= off) ? sh[tid - off] : 0;
      __syncthreads();
      sh[tid] += t;
      __syncthreads();
    }
    const int incl = sh[tid];
    const int c = carry_sh;
    if (i < n) {
      const int ro = c + incl - v;
      row_off[i] = ro;
      cursor[i] = ro;
      deg_inv[i] = 1.0f / (float)((v > 1) ? v : 1);
    }
    __syncthreads();
    if (tid == SCAN_B - 1) carry_sh = c + incl;
    __syncthreads();
  }
  if (tid == 0) row_off[n] = carry_sh;
}

__global__ void k_fill_csr(const int* __restrict__ src, const int* __restrict__ dst,
                           int* __restrict__ cursor, int* __restrict__ esrc, int E) {
  int e = blockIdx.x * blockDim.x + threadIdx.x;
  if (e < E) {
    int d = dst[e];
    int p = atomicAdd(cursor + d, 1);
    esrc[p] = src[e];
  }
}

// ---------------- f32 -> bf16 conversion (x + all weights, one launch) ------
struct ConvJob { const float* src; unsigned short* dst; int n; };
struct ConvJobs { ConvJob j[11]; };

__global__ __launch_bounds__(256)
void k_f32_to_bf16(ConvJobs jobs) {
  const ConvJob J = jobs.j[blockIdx.y];
  for (int i = blockIdx.x * blockDim.x + threadIdx.x; i < J.n; i += gridDim.x * blockDim.x)
    J.dst[i] = f2bf(J.src[i]);
}

// ---------------- mean aggregation (bf16 in/out, f32 accum) ----------------
// 4 nodes per 256-thread block; one wave per node; ACT lanes each own UPL uints
// (2 bf16 per uint) of the K-wide row.
template <int UPL, int ACT>
__global__ __launch_bounds__(256)
void k_aggregate(const unsigned short* __restrict__ h, const int* __restrict__ row_off,
                 const int* __restrict__ esrc, const float* __restrict__ deg_inv,
                 unsigned short* __restrict__ agg, int N) {
  const int node = blockIdx.x * 4 + (threadIdx.x >> 6);
  if (node >= N) return;
  const int lane = threadIdx.x & 63;
  if (ACT < 64 && lane >= ACT) return;
  const int s0 = row_off[node], s1 = row_off[node + 1];
  const unsigned int* hp = (const unsigned int*)h;
  float accl[UPL], acch[UPL];
#pragma unroll
  for (int u = 0; u < UPL; ++u) { accl[u] = 0.f; acch[u] = 0.f; }
  for (int i = s0; i < s1; ++i) {
    const size_t base = (size_t)esrc[i] * (UPL * ACT);
#pragma unroll
    for (int u = 0; u < UPL; ++u) {
      const unsigned int v = hp[base + u * ACT + lane];
      accl[u] += bf2f((unsigned short)(v & 0xffffu));
      acch[u] += bf2f((unsigned short)(v >> 16));
    }
  }
  const float di = deg_inv[node];
  unsigned int* ap = (unsigned int*)agg;
#pragma unroll
  for (int u = 0; u < UPL; ++u) {
    const unsigned int o =
        (unsigned int)f2bf(accl[u] * di) | ((unsigned int)f2bf(acch[u] * di) << 16);
    ap[(size_t)node * (UPL * ACT) + u * ACT + lane] = o;
  }
}

// ---------------- fused SAGE GEMM: C = relu(A0@B0^T + A1@B1^T + bias) ------
// bf16 in, f32 MFMA accum, bf16 out. 64x64 per wave (4x4 16x16 frags),
// operands direct from global. K%32==0, O%(BNW*64)==0.
template <int BMW, int BNW>
__global__ __launch_bounds__(BMW * BNW * 64)
void k_sage_gemm(const unsigned short* __restrict__ A0, const unsigned short* __restrict__ B0,
                 const unsigned short* __restrict__ A1, const unsigned short* __restrict__ B1,
                 const float* __restrict__ bias, unsigned short* __restrict__ C,
                 int Nn, int K, int O) {
  const int w = threadIdx.x >> 6;
  const int lane = threadIdx.x & 63;
  const int wr = w / BNW, wc = w % BNW;
  const int row0 = blockIdx.x * (BMW * 64) + wr * 64;
  const int col0 = blockIdx.y * (BNW * 64) + wc * 64;
  const int fr = lane & 15;   // A-row / B-col within frag
  const int fq = lane >> 4;   // k-chunk selector (8 bf16 each)

  f32x4 acc[4][4];
#pragma unroll
  for (int m = 0; m < 4; ++m)
#pragma unroll
    for (int n = 0; n < 4; ++n) acc[m][n] = (f32x4){0.f, 0.f, 0.f, 0.f};

  int arow[4];
#pragma unroll
  for (int m = 0; m < 4; ++m) {
    int r = row0 + m * 16 + fr;
    arow[m] = (r < Nn) ? r : (Nn - 1);  // clamp; stores are masked
  }

#pragma unroll 1
  for (int phase = 0; phase < 2; ++phase) {
    const unsigned short* __restrict__ A = phase ? A1 : A0;
    const unsigned short* __restrict__ B = phase ? B1 : B0;
    for (int kt = 0; kt < K; kt += 32) {
      bf16x8 af[4], bg[4];
#pragma unroll
      for (int m = 0; m < 4; ++m)
        af[m] = *(const bf16x8*)(A + (size_t)arow[m] * K + kt + fq * 8);
#pragma unroll
      for (int n = 0; n < 4; ++n)
        bg[n] = *(const bf16x8*)(B + (size_t)(col0 + n * 16 + fr) * K + kt + fq * 8);
#pragma unroll
      for (int m = 0; m < 4; ++m)
#pragma unroll
        for (int n = 0; n < 4; ++n)
          acc[m][n] = __builtin_amdgcn_mfma_f32_16x16x32_bf16(af[m], bg[n], acc[m][n], 0, 0, 0);
    }
  }

  // epilogue: bias + relu + bf16 store. C/D map: col=lane&15, row=(lane>>4)*4+j
#pragma unroll
  for (int n = 0; n < 4; ++n) {
    const int col = col0 + n * 16 + fr;
    const float bb = bias[col];
#pragma unroll
    for (int m = 0; m < 4; ++m) {
#pragma unroll
      for (int j = 0; j < 4; ++j) {
        const int row = row0 + m * 16 + fq * 4 + j;
        if (row < Nn) {
          const float v = fmaxf(acc[m][n][j] + bb, 0.f);
          C[(size_t)row * O + col] = f2bf(v);
        }
      }
    }
  }
}

// ---------------- head: logits(512->4) + softmax, one wave per node --------
__global__ __launch_bounds__(64)
void k_out_softmax(const unsigned short* __restrict__ h, const float* __restrict__ W4,
                   const float* __restrict__ b, float* __restrict__ out) {
  const int n = blockIdx.x;
  const int lane = threadIdx.x;
  const unsigned int* hp = (const unsigned int*)h + (size_t)n * 256;
  float a[4] = {0.f, 0.f, 0.f, 0.f};
#pragma unroll
  for (int it = 0; it < 4; ++it) {
    const unsigned int v = hp[it * 64 + lane];
    const float lo = bf2f((unsigned short)(v & 0xffffu));
    const float hi = bf2f((unsigned short)(v >> 16));
    const int k = (it * 64 + lane) * 2;
#pragma unroll
    for (int c = 0; c < 4; ++c)
      a[c] += lo * W4[c * 512 + k] + hi * W4[c * 512 + k + 1];
  }
#pragma unroll
  for (int off = 32; off > 0; off >>= 1) {
#pragma unroll
    for (int c = 0; c < 4; ++c) a[c] += __shfl_down(a[c], off);
  }
  if (lane == 0) {
    const float l0 = a[0] + b[0], l1 = a[1] + b[1], l2 = a[2] + b[2], l3 = a[3] + b[3];
    const float m = fmaxf(fmaxf(l0, l1), fmaxf(l2, l3));
    const float e0 = expf(l0 - m), e1 = expf(l1 - m), e2 = expf(l2 - m), e3 = expf(l3 - m);
    const float inv = 1.0f / (e0 + e1 + e2 + e3);
    float4 r; r.x = e0 * inv; r.y = e1 * inv; r.z = e2 * inv; r.w = e3 * inv;
    *(float4*)(out + (size_t)n * 4) = r;
  }
}

// ---------------------------------------------------------------------------
extern "C" void kernel_launch(void* const* d_in, const int* in_sizes, int n_in,
                              void* d_out, int out_size, void* d_ws, size_t ws_size,
                              hipStream_t stream) {
  const float* x = (const float*)d_in[0];
  const float* Wl[5] = {(const float*)d_in[1], (const float*)d_in[4], (const float*)d_in[7],
                        (const float*)d_in[10], (const float*)d_in[13]};
  const float* bl[5] = {(const float*)d_in[2], (const float*)d_in[5], (const float*)d_in[8],
                        (const float*)d_in[11], (const float*)d_in[14]};
  const float* Wr[5] = {(const float*)d_in[3], (const float*)d_in[6], (const float*)d_in[9],
                        (const float*)d_in[12], (const float*)d_in[15]};
  const float* Wout = (const float*)d_in[16];
  const float* bout = (const float*)d_in[17];
  const int* eidx = (const int*)d_in[18];

  const int N = in_sizes[0] / 128;
  const int E = in_sizes[18] / 2;
  const int* srcI = eidx;
  const int* dstI = eidx + E;

  const int Kd[5] = {128, 128, 64, 128, 256};
  const int Od[5] = {128, 64, 128, 256, 512};

  // workspace carve-out (256B aligned)
  char* ws = (char*)d_ws;
  size_t p = 0;
  auto alloc = [&](size_t bytes) { size_t r = p; p += (bytes + 255) & ~(size_t)255; return r; };
  int*   deg     = (int*)(ws + alloc((size_t)N * 4));
  int*   row_off = (int*)(ws + alloc((size_t)(N + 1) * 4));
  int*   cursor  = (int*)(ws + alloc((size_t)N * 4));
  float* deg_inv = (float*)(ws + alloc((size_t)N * 4));
  int*   esrc    = (int*)(ws + alloc((size_t)E * 4));
  unsigned short* xb   = (unsigned short*)(ws + alloc((size_t)N * 128 * 2));
  unsigned short* wlb[5];
  unsigned short* wrb[5];
  for (int l = 0; l < 5; ++l) {
    wlb[l] = (unsigned short*)(ws + alloc((size_t)Od[l] * Kd[l] * 2));
    wrb[l] = (unsigned short*)(ws + alloc((size_t)Od[l] * Kd[l] * 2));
  }
  unsigned short* bufA = (unsigned short*)(ws + alloc((size_t)N * 512 * 2));
  unsigned short* bufB = (unsigned short*)(ws + alloc((size_t)N * 256 * 2));
  unsigned short* agg  = (unsigned short*)(ws + alloc((size_t)N * 256 * 2));
  (void)ws_size; (void)n_in; (void)out_size;

  // ---- conversions (x + 10 weight mats) in one launch ----
  ConvJobs jobs;
  jobs.j[0] = {x, xb, N * 128};
  for (int l = 0; l < 5; ++l) {
    jobs.j[1 + 2 * l] = {Wl[l], wlb[l], Od[l] * Kd[l]};
    jobs.j[2 + 2 * l] = {Wr[l], wrb[l], Od[l] * Kd[l]};
  }
  k_f32_to_bf16<<<dim3(256, 11), 256, 0, stream>>>(jobs);

  // ---- CSR build ----
  k_zero_int<<<idiv_up(N, 256), 256, 0, stream>>>(deg, N);
  k_count_deg<<<idiv_up(E, 256), 256, 0, stream>>>(dstI, deg, E);
  k_scan<<<1, SCAN_B, 0, stream>>>(deg, row_off, cursor, deg_inv, N);
  k_fill_csr<<<idiv_up(E, 256), 256, 0, stream>>>(srcI, dstI, cursor, esrc, E);

  unsigned short* houts[5] = {bufA, bufB, bufA, bufB, bufA};

  const unsigned short* hin = xb;
  for (int l = 0; l < 5; ++l) {
    const int K = Kd[l], O = Od[l];
    // aggregate
    if (K == 64)
      k_aggregate<1, 32><<<idiv_up(N, 4), 256, 0, stream>>>(hin, row_off, esrc, deg_inv, agg, N);
    else if (K == 128)
      k_aggregate<1, 64><<<idiv_up(N, 4), 256, 0, stream>>>(hin, row_off, esrc, deg_inv, agg, N);
    else
      k_aggregate<2, 64><<<idiv_up(N, 4), 256, 0, stream>>>(hin, row_off, esrc, deg_inv, agg, N);

    // fused GEMM + bias + relu
    unsigned short* hout = houts[l];
    if (O == 64) {
      k_sage_gemm<4, 1><<<dim3(idiv_up(N, 256), 1), 256, 0, stream>>>(
          agg, wlb[l], hin, wrb[l], bl[l], hout, N, K, O);
    } else {
      k_sage_gemm<2, 2><<<dim3(idiv_up(N, 128), O / 128), 256, 0, stream>>>(
          agg, wlb[l], hin, wrb[l], bl[l], hout, N, K, O);
    }
    hin = hout;
  }
  k_out_softmax<<<N, 64, 0, stream>>>(hin, Wout, bout, (float*)d_out);
}

// Round 4
// 614.575 us; speedup vs baseline: 2.0702x; 1.4239x over previous
//
#include <hip/hip_runtime.h>
#include <hip/hip_bf16.h>
#include <cstdint>
#include <cstddef>

// ---------------------------------------------------------------------------
// SAGE GNN forward, bf16 + MFMA 32x32x16 edition.
//  - GEMM: full-O-width blocks (A read once), shfl-packed u32 C stores
//  - aggregate: 4 gathers in flight per wave
//  - CSR: wave-shfl scan
// ---------------------------------------------------------------------------

typedef short bf16x8 __attribute__((ext_vector_type(8)));   // 8 bf16 = 4 VGPRs
typedef float f32x16 __attribute__((ext_vector_type(16)));

static inline int idiv_up(int a, int b) { return (a + b - 1) / b; }

static __device__ __forceinline__ float bf2f(unsigned short u) {
  union { unsigned int i; float f; } v; v.i = ((unsigned int)u) << 16; return v.f;
}
static __device__ __forceinline__ unsigned short f2bf(float f) {
  union { float f; unsigned int i; } v; v.f = f;
  return (unsigned short)((v.i + 0x7FFFu + ((v.i >> 16) & 1u)) >> 16);  // RNE
}
static __device__ __forceinline__ float lo16(unsigned int u) { return bf2f((unsigned short)(u & 0xffffu)); }
static __device__ __forceinline__ float hi16(unsigned int u) { return bf2f((unsigned short)(u >> 16)); }
static __device__ __forceinline__ unsigned int packbf(float a, float b) {
  return (unsigned int)f2bf(a) | ((unsigned int)f2bf(b) << 16);
}

// ---------------- CSR build ----------------
__global__ void k_zero_int(int* __restrict__ p, int n) {
  int i = blockIdx.x * blockDim.x + threadIdx.x;
  if (i < n) p[i] = 0;
}

__global__ void k_count_deg(const int* __restrict__ dst, int* __restrict__ deg, int E) {
  int e = blockIdx.x * blockDim.x + threadIdx.x;
  if (e < E) atomicAdd(deg + dst[e], 1);
}

// wave-shfl hierarchical scan, 1024 threads, chunked.
__global__ __launch_bounds__(1024)
void k_scan(const int* __restrict__ deg, int* __restrict__ row_off, int* __restrict__ cursor,
            float* __restrict__ deg_inv, int n) {
  __shared__ int wsum[16];
  const int tid = threadIdx.x;
  const int lane = tid & 63, wid = tid >> 6;
  int carry = 0;
  for (int base = 0; base < n; base += 1024) {
    const int i = base + tid;
    const int v = (i < n) ? deg[i] : 0;
    int incl = v;
#pragma unroll
    for (int off = 1; off < 64; off <<= 1) {
      int t = __shfl_up(incl, off);
      if (lane >= off) incl += t;
    }
    if (lane == 63) wsum[wid] = incl;
    __syncthreads();
    if (wid == 0) {
      int wv = (lane < 16) ? wsum[lane] : 0;
#pragma unroll
      for (int off = 1; off < 16; off <<= 1) {
        int t = __shfl_up(wv, off);
        if (lane >= off) wv += t;
      }
      if (lane < 16) wsum[lane] = wv;
    }
    __syncthreads();
    const int woff = (wid > 0) ? wsum[wid - 1] : 0;
    if (i < n) {
      const int ro = carry + woff + incl - v;
      row_off[i] = ro;
      cursor[i] = ro;
      deg_inv[i] = 1.0f / (float)((v > 1) ? v : 1);
    }
    const int tot = wsum[15];
    __syncthreads();
    carry += tot;
  }
  if (tid == 0) row_off[n] = carry;
}

__global__ void k_fill_csr(const int* __restrict__ src, const int* __restrict__ dst,
                           int* __restrict__ cursor, int* __restrict__ esrc, int E) {
  int e = blockIdx.x * blockDim.x + threadIdx.x;
  if (e < E) {
    int d = dst[e];
    int p = atomicAdd(cursor + d, 1);
    esrc[p] = src[e];
  }
}

// ---------------- f32 -> bf16 conversion (x + all weights, one launch) ------
struct ConvJob { const float* src; unsigned short* dst; int n4; };  // n4 = n/4
struct ConvJobs { ConvJob j[11]; };

__global__ __launch_bounds__(256)
void k_f32_to_bf16(ConvJobs jobs) {
  const ConvJob J = jobs.j[blockIdx.y];
  for (int i = blockIdx.x * blockDim.x + threadIdx.x; i < J.n4; i += gridDim.x * blockDim.x) {
    const float4 v = *((const float4*)J.src + i);
    uint2 o;
    o.x = packbf(v.x, v.y);
    o.y = packbf(v.z, v.w);
    *((uint2*)J.dst + i) = o;
  }
}

// ---------------- mean aggregation, bf16 in/out, f32 accum -----------------
// K=128: one wave per node, 64 u32 per row, edge loop unrolled x4.
__global__ __launch_bounds__(256)
void k_agg128(const unsigned short* __restrict__ h, const int* __restrict__ row_off,
              const int* __restrict__ esrc, const float* __restrict__ deg_inv,
              unsigned short* __restrict__ agg, int N) {
  const int node = blockIdx.x * 4 + (threadIdx.x >> 6);
  if (node >= N) return;
  const int lane = threadIdx.x & 63;
  const int s0 = row_off[node], s1 = row_off[node + 1];
  const unsigned int* hp = (const unsigned int*)h;
  float al = 0.f, ah = 0.f;
  int i = s0;
  for (; i + 4 <= s1; i += 4) {
    const unsigned int u0 = hp[(size_t)esrc[i] * 64 + lane];
    const unsigned int u1 = hp[(size_t)esrc[i + 1] * 64 + lane];
    const unsigned int u2 = hp[(size_t)esrc[i + 2] * 64 + lane];
    const unsigned int u3 = hp[(size_t)esrc[i + 3] * 64 + lane];
    al += lo16(u0) + lo16(u1) + lo16(u2) + lo16(u3);
    ah += hi16(u0) + hi16(u1) + hi16(u2) + hi16(u3);
  }
  for (; i < s1; ++i) {
    const unsigned int u = hp[(size_t)esrc[i] * 64 + lane];
    al += lo16(u); ah += hi16(u);
  }
  const float di = deg_inv[node];
  ((unsigned int*)agg)[(size_t)node * 64 + lane] = packbf(al * di, ah * di);
}

// K=256: one wave per node, 128 u32 per row (lane owns lane, lane+64), unroll x2.
__global__ __launch_bounds__(256)
void k_agg256(const unsigned short* __restrict__ h, const int* __restrict__ row_off,
              const int* __restrict__ esrc, const float* __restrict__ deg_inv,
              unsigned short* __restrict__ agg, int N) {
  const int node = blockIdx.x * 4 + (threadIdx.x >> 6);
  if (node >= N) return;
  const int lane = threadIdx.x & 63;
  const int s0 = row_off[node], s1 = row_off[node + 1];
  const unsigned int* hp = (const unsigned int*)h;
  float al = 0.f, ah = 0.f, bl_ = 0.f, bh = 0.f;
  int i = s0;
  for (; i + 2 <= s1; i += 2) {
    const size_t b0 = (size_t)esrc[i] * 128;
    const size_t b1 = (size_t)esrc[i + 1] * 128;
    const unsigned int u0 = hp[b0 + lane];
    const unsigned int u1 = hp[b0 + 64 + lane];
    const unsigned int u2 = hp[b1 + lane];
    const unsigned int u3 = hp[b1 + 64 + lane];
    al += lo16(u0) + lo16(u2); ah += hi16(u0) + hi16(u2);
    bl_ += lo16(u1) + lo16(u3); bh += hi16(u1) + hi16(u3);
  }
  if (i < s1) {
    const size_t b0 = (size_t)esrc[i] * 128;
    const unsigned int u0 = hp[b0 + lane];
    const unsigned int u1 = hp[b0 + 64 + lane];
    al += lo16(u0); ah += hi16(u0);
    bl_ += lo16(u1); bh += hi16(u1);
  }
  const float di = deg_inv[node];
  unsigned int* ap = (unsigned int*)agg;
  ap[(size_t)node * 128 + lane] = packbf(al * di, ah * di);
  ap[(size_t)node * 128 + 64 + lane] = packbf(bl_ * di, bh * di);
}

// K=64: 32 u32 per row; wave halves take alternating edges, shfl_xor(32) combine.
__global__ __launch_bounds__(256)
void k_agg64(const unsigned short* __restrict__ h, const int* __restrict__ row_off,
             const int* __restrict__ esrc, const float* __restrict__ deg_inv,
             unsigned short* __restrict__ agg, int N) {
  const int node = blockIdx.x * 4 + (threadIdx.x >> 6);
  if (node >= N) return;
  const int lane = threadIdx.x & 63;
  const int half = lane >> 5, c = lane & 31;
  const int s0 = row_off[node], s1 = row_off[node + 1];
  const unsigned int* hp = (const unsigned int*)h;
  float al = 0.f, ah = 0.f;
  int i = s0 + half;
  for (; i + 2 < s1; i += 4) {  // edges i and i+2 for this half
    const unsigned int u0 = hp[(size_t)esrc[i] * 32 + c];
    const unsigned int u1 = hp[(size_t)esrc[i + 2] * 32 + c];
    al += lo16(u0) + lo16(u1);
    ah += hi16(u0) + hi16(u1);
  }
  if (i < s1) {
    const unsigned int u = hp[(size_t)esrc[i] * 32 + c];
    al += lo16(u); ah += hi16(u);
  }
  al += __shfl_xor(al, 32);
  ah += __shfl_xor(ah, 32);
  if (half == 0) {
    const float di = deg_inv[node];
    ((unsigned int*)agg)[(size_t)node * 32 + c] = packbf(al * di, ah * di);
  }
}

// ---------------- fused SAGE GEMM: C = relu(A0@B0^T + A1@B1^T + bias) ------
// MFMA 32x32x16 bf16, wave tile 64x64 (2x2 frags), block tile (WR*64)x(WC*64),
// WC*64 == O (full output width -> A read exactly once). Operands direct from
// global (B is L2-resident). C stores: shfl-packed u32, 64B segments.
template <int WR, int WC>
__global__ __launch_bounds__(WR * WC * 64)
void k_sage_gemm(const unsigned short* __restrict__ A0, const unsigned short* __restrict__ B0,
                 const unsigned short* __restrict__ A1, const unsigned short* __restrict__ B1,
                 const float* __restrict__ bias, unsigned short* __restrict__ C,
                 int Nn, int K) {
  const int O = WC * 64;
  const int w = threadIdx.x >> 6;
  const int lane = threadIdx.x & 63;
  const int wr = w / WC, wc = w % WC;
  const int fr = lane & 31;   // row (A) / col (B) within 32-frag
  const int fq = lane >> 5;   // k-chunk selector (8 bf16)
  const int row0 = blockIdx.x * (WR * 64) + wr * 64;
  const int col0 = wc * 64;

  f32x16 acc[2][2];
#pragma unroll
  for (int m = 0; m < 2; ++m)
#pragma unroll
    for (int cn = 0; cn < 2; ++cn)
#pragma unroll
      for (int r = 0; r < 16; ++r) acc[m][cn][r] = 0.f;

  int arow[2];
#pragma unroll
  for (int m = 0; m < 2; ++m) {
    const int r = row0 + m * 32 + fr;
    arow[m] = (r < Nn) ? r : (Nn - 1);  // clamp; stores masked by row
  }

#pragma unroll 1
  for (int phase = 0; phase < 2; ++phase) {
    const unsigned short* __restrict__ A = phase ? A1 : A0;
    const unsigned short* __restrict__ B = phase ? B1 : B0;
    for (int kt = 0; kt < K; kt += 16) {
      bf16x8 af[2], bg[2];
#pragma unroll
      for (int m = 0; m < 2; ++m)
        af[m] = *(const bf16x8*)(A + (size_t)arow[m] * K + kt + fq * 8);
#pragma unroll
      for (int cn = 0; cn < 2; ++cn)
        bg[cn] = *(const bf16x8*)(B + (size_t)(col0 + cn * 32 + fr) * K + kt + fq * 8);
#pragma unroll
      for (int m = 0; m < 2; ++m)
#pragma unroll
        for (int cn = 0; cn < 2; ++cn)
          acc[m][cn] = __builtin_amdgcn_mfma_f32_32x32x16_bf16(af[m], bg[cn], acc[m][cn], 0, 0, 0);
    }
  }

  // epilogue. C/D map: col = lane&31, row = (reg&3) + 8*(reg>>2) + 4*(lane>>5).
#pragma unroll
  for (int cn = 0; cn < 2; ++cn) {
    const int col = col0 + cn * 32 + fr;
    const float bb = bias[col];
#pragma unroll
    for (int m = 0; m < 2; ++m) {
#pragma unroll
      for (int reg = 0; reg < 16; ++reg) {
        const float v = fmaxf(acc[m][cn][reg] + bb, 0.f);
        const float nb = __shfl_xor(v, 1);  // odd lane's value into even lane
        const int row = row0 + m * 32 + (reg & 3) + 8 * (reg >> 2) + 4 * fq;
        if (!(lane & 1) && row < Nn) {
          *(unsigned int*)(C + (size_t)row * O + col) = packbf(v, nb);
        }
      }
    }
  }
}

// ---------------- head: logits(512->4) + softmax, one wave per node --------
__global__ __launch_bounds__(64)
void k_out_softmax(const unsigned short* __restrict__ h, const float* __restrict__ W4,
                   const float* __restrict__ b, float* __restrict__ out) {
  const int n = blockIdx.x;
  const int lane = threadIdx.x;
  const unsigned int* hp = (const unsigned int*)h + (size_t)n * 256;
  float a[4] = {0.f, 0.f, 0.f, 0.f};
#pragma unroll
  for (int it = 0; it < 4; ++it) {
    const unsigned int v = hp[it * 64 + lane];
    const float lo = lo16(v);
    const float hi = hi16(v);
    const int k = (it * 64 + lane) * 2;
#pragma unroll
    for (int c = 0; c < 4; ++c)
      a[c] += lo * W4[c * 512 + k] + hi * W4[c * 512 + k + 1];
  }
#pragma unroll
  for (int off = 32; off > 0; off >>= 1) {
#pragma unroll
    for (int c = 0; c < 4; ++c) a[c] += __shfl_down(a[c], off);
  }
  if (lane == 0) {
    const float l0 = a[0] + b[0], l1 = a[1] + b[1], l2 = a[2] + b[2], l3 = a[3] + b[3];
    const float m = fmaxf(fmaxf(l0, l1), fmaxf(l2, l3));
    const float e0 = expf(l0 - m), e1 = expf(l1 - m), e2 = expf(l2 - m), e3 = expf(l3 - m);
    const float inv = 1.0f / (e0 + e1 + e2 + e3);
    float4 r; r.x = e0 * inv; r.y = e1 * inv; r.z = e2 * inv; r.w = e3 * inv;
    *(float4*)(out + (size_t)n * 4) = r;
  }
}

// ---------------------------------------------------------------------------
extern "C" void kernel_launch(void* const* d_in, const int* in_sizes, int n_in,
                              void* d_out, int out_size, void* d_ws, size_t ws_size,
                              hipStream_t stream) {
  const float* x = (const float*)d_in[0];
  const float* Wl[5] = {(const float*)d_in[1], (const float*)d_in[4], (const float*)d_in[7],
                        (const float*)d_in[10], (const float*)d_in[13]};
  const float* bl[5] = {(const float*)d_in[2], (const float*)d_in[5], (const float*)d_in[8],
                        (const float*)d_in[11], (const float*)d_in[14]};
  const float* Wr[5] = {(const float*)d_in[3], (const float*)d_in[6], (const float*)d_in[9],
                        (const float*)d_in[12], (const float*)d_in[15]};
  const float* Wout = (const float*)d_in[16];
  const float* bout = (const float*)d_in[17];
  const int* eidx = (const int*)d_in[18];

  const int N = in_sizes[0] / 128;
  const int E = in_sizes[18] / 2;
  const int* srcI = eidx;
  const int* dstI = eidx + E;

  const int Kd[5] = {128, 128, 64, 128, 256};
  const int Od[5] = {128, 64, 128, 256, 512};

  // workspace carve-out (256B aligned)
  char* ws = (char*)d_ws;
  size_t p = 0;
  auto alloc = [&](size_t bytes) { size_t r = p; p += (bytes + 255) & ~(size_t)255; return r; };
  int*   deg     = (int*)(ws + alloc((size_t)N * 4));
  int*   row_off = (int*)(ws + alloc((size_t)(N + 1) * 4));
  int*   cursor  = (int*)(ws + alloc((size_t)N * 4));
  float* deg_inv = (float*)(ws + alloc((size_t)N * 4));
  int*   esrc    = (int*)(ws + alloc((size_t)E * 4));
  unsigned short* xb = (unsigned short*)(ws + alloc((size_t)N * 128 * 2));
  unsigned short* wlb[5];
  unsigned short* wrb[5];
  for (int l = 0; l < 5; ++l) {
    wlb[l] = (unsigned short*)(ws + alloc((size_t)Od[l] * Kd[l] * 2));
    wrb[l] = (unsigned short*)(ws + alloc((size_t)Od[l] * Kd[l] * 2));
  }
  unsigned short* bufA = (unsigned short*)(ws + alloc((size_t)N * 512 * 2));
  unsigned short* bufB = (unsigned short*)(ws + alloc((size_t)N * 256 * 2));
  unsigned short* agg  = (unsigned short*)(ws + alloc((size_t)N * 256 * 2));
  (void)ws_size; (void)n_in; (void)out_size;

  // ---- conversions (x + 10 weight mats) in one launch ----
  ConvJobs jobs;
  jobs.j[0] = {x, xb, N * 128 / 4};
  for (int l = 0; l < 5; ++l) {
    jobs.j[1 + 2 * l] = {Wl[l], wlb[l], Od[l] * Kd[l] / 4};
    jobs.j[2 + 2 * l] = {Wr[l], wrb[l], Od[l] * Kd[l] / 4};
  }
  k_f32_to_bf16<<<dim3(128, 11), 256, 0, stream>>>(jobs);

  // ---- CSR build ----
  k_zero_int<<<idiv_up(N, 256), 256, 0, stream>>>(deg, N);
  k_count_deg<<<idiv_up(E, 256), 256, 0, stream>>>(dstI, deg, E);
  k_scan<<<1, 1024, 0, stream>>>(deg, row_off, cursor, deg_inv, N);
  k_fill_csr<<<idiv_up(E, 256), 256, 0, stream>>>(srcI, dstI, cursor, esrc, E);

  unsigned short* houts[5] = {bufA, bufB, bufA, bufB, bufA};

  const unsigned short* hin = xb;
  for (int l = 0; l < 5; ++l) {
    const int K = Kd[l];
    // aggregate
    if (K == 64)
      k_agg64<<<idiv_up(N, 4), 256, 0, stream>>>(hin, row_off, esrc, deg_inv, agg, N);
    else if (K == 128)
      k_agg128<<<idiv_up(N, 4), 256, 0, stream>>>(hin, row_off, esrc, deg_inv, agg, N);
    else
      k_agg256<<<idiv_up(N, 4), 256, 0, stream>>>(hin, row_off, esrc, deg_inv, agg, N);

    // fused GEMM + bias + relu (full-O-width blocks)
    unsigned short* hout = houts[l];
    switch (l) {
      case 0:  // K=128, O=128
        k_sage_gemm<2, 2><<<idiv_up(N, 128), 256, 0, stream>>>(agg, wlb[l], hin, wrb[l], bl[l], hout, N, K);
        break;
      case 1:  // K=128, O=64
        k_sage_gemm<4, 1><<<idiv_up(N, 256), 256, 0, stream>>>(agg, wlb[l], hin, wrb[l], bl[l], hout, N, K);
        break;
      case 2:  // K=64, O=128
        k_sage_gemm<2, 2><<<idiv_up(N, 128), 256, 0, stream>>>(agg, wlb[l], hin, wrb[l], bl[l], hout, N, K);
        break;
      case 3:  // K=128, O=256
        k_sage_gemm<2, 4><<<idiv_up(N, 128), 512, 0, stream>>>(agg, wlb[l], hin, wrb[l], bl[l], hout, N, K);
        break;
      default: // K=256, O=512
        k_sage_gemm<2, 8><<<idiv_up(N, 128), 1024, 0, stream>>>(agg, wlb[l], hin, wrb[l], bl[l], hout, N, K);
        break;
    }
    hin = hout;
  }
  k_out_softmax<<<N, 64, 0, stream>>>(hin, Wout, bout, (float*)d_out);
}

// Round 5
// 527.617 us; speedup vs baseline: 2.4113x; 1.1648x over previous
//
#include <hip/hip_runtime.h>
#include <hip/hip_bf16.h>
#include <cstdint>
#include <cstddef>

// ---------------------------------------------------------------------------
// SAGE GNN forward, bf16 MFMA 32x32x16 + LDS-staged GEMM (global_load_lds).
//  - B weights pre-packed [ktile][col][chunk^(col&3)] -> contiguous staging
//  - A staged with swizzled global source, linear LDS dest (rule 21)
//  - double buffer, vmcnt(0)+barrier per 32-wide K-step
// ---------------------------------------------------------------------------

typedef short bf16x8 __attribute__((ext_vector_type(8)));   // 8 bf16 = 4 VGPRs
typedef float f32x16 __attribute__((ext_vector_type(16)));

static inline int idiv_up(int a, int b) { return (a + b - 1) / b; }

static __device__ __forceinline__ float bf2f(unsigned short u) {
  union { unsigned int i; float f; } v; v.i = ((unsigned int)u) << 16; return v.f;
}
static __device__ __forceinline__ unsigned short f2bf(float f) {
  union { float f; unsigned int i; } v; v.f = f;
  return (unsigned short)((v.i + 0x7FFFu + ((v.i >> 16) & 1u)) >> 16);  // RNE
}
static __device__ __forceinline__ float lo16(unsigned int u) { return bf2f((unsigned short)(u & 0xffffu)); }
static __device__ __forceinline__ float hi16(unsigned int u) { return bf2f((unsigned short)(u >> 16)); }
static __device__ __forceinline__ unsigned int packbf(float a, float b) {
  return (unsigned int)f2bf(a) | ((unsigned int)f2bf(b) << 16);
}

// async global->LDS, 16B per lane. LDS dest: wave-uniform base + lane*16.
static __device__ __forceinline__ void gl_lds16(const void* g, void* l) {
  typedef __attribute__((address_space(3))) unsigned int lds_u32;
  typedef __attribute__((address_space(1))) const unsigned int glb_u32;
  __builtin_amdgcn_global_load_lds((glb_u32*)(uintptr_t)g,
                                   (lds_u32*)(unsigned int)(uintptr_t)l, 16, 0, 0);
}

// ---------------- CSR build ----------------
__global__ void k_zero_int(int* __restrict__ p, int n) {
  int i = blockIdx.x * blockDim.x + threadIdx.x;
  if (i < n) p[i] = 0;
}

__global__ void k_count_deg(const int* __restrict__ dst, int* __restrict__ deg, int E) {
  int e = blockIdx.x * blockDim.x + threadIdx.x;
  if (e < E) atomicAdd(deg + dst[e], 1);
}

// wave-shfl hierarchical scan, 1024 threads, chunked.
__global__ __launch_bounds__(1024)
void k_scan(const int* __restrict__ deg, int* __restrict__ row_off, int* __restrict__ cursor,
            float* __restrict__ deg_inv, int n) {
  __shared__ int wsum[16];
  const int tid = threadIdx.x;
  const int lane = tid & 63, wid = tid >> 6;
  int carry = 0;
  for (int base = 0; base < n; base += 1024) {
    const int i = base + tid;
    const int v = (i < n) ? deg[i] : 0;
    int incl = v;
#pragma unroll
    for (int off = 1; off < 64; off <<= 1) {
      int t = __shfl_up(incl, off);
      if (lane >= off) incl += t;
    }
    if (lane == 63) wsum[wid] = incl;
    __syncthreads();
    if (wid == 0) {
      int wv = (lane < 16) ? wsum[lane] : 0;
#pragma unroll
      for (int off = 1; off < 16; off <<= 1) {
        int t = __shfl_up(wv, off);
        if (lane >= off) wv += t;
      }
      if (lane < 16) wsum[lane] = wv;
    }
    __syncthreads();
    const int woff = (wid > 0) ? wsum[wid - 1] : 0;
    if (i < n) {
      const int ro = carry + woff + incl - v;
      row_off[i] = ro;
      cursor[i] = ro;
      deg_inv[i] = 1.0f / (float)((v > 1) ? v : 1);
    }
    const int tot = wsum[15];
    __syncthreads();
    carry += tot;
  }
  if (tid == 0) row_off[n] = carry;
}

__global__ void k_fill_csr(const int* __restrict__ src, const int* __restrict__ dst,
                           int* __restrict__ cursor, int* __restrict__ esrc, int E) {
  int e = blockIdx.x * blockDim.x + threadIdx.x;
  if (e < E) {
    int d = dst[e];
    int p = atomicAdd(cursor + d, 1);
    esrc[p] = src[e];
  }
}

// ---------------- x: f32 -> bf16 plain conversion --------------------------
__global__ __launch_bounds__(256)
void k_conv_x(const float* __restrict__ src, unsigned short* __restrict__ dst, int n4) {
  for (int i = blockIdx.x * blockDim.x + threadIdx.x; i < n4; i += gridDim.x * blockDim.x) {
    const float4 v = *((const float4*)src + i);
    uint2 o;
    o.x = packbf(v.x, v.y);
    o.y = packbf(v.z, v.w);
    *((uint2*)dst + i) = o;
  }
}

// ---------------- weights: f32 -> bf16 packed tile layout ------------------
// dst elem index e = ktile*(O*32) + col*32 + s*8 + j  holds
// src[col][ktile*32 + (s^(col&3))*8 + j].   (chunk swizzle baked in)
struct PackJob { const float* src; unsigned short* dst; int O; int K; };
struct PackJobs { PackJob j[10]; };

__global__ __launch_bounds__(256)
void k_pack_w(PackJobs jobs) {
  const PackJob J = jobs.j[blockIdx.y];
  const int total = J.O * J.K / 2;  // u32 outputs
  const int OK32 = J.O * 32;
  for (int u = blockIdx.x * blockDim.x + threadIdx.x; u < total; u += gridDim.x * blockDim.x) {
    const int e = u * 2;
    const int ktile = e / OK32;
    const int rem = e - ktile * OK32;
    const int col = rem >> 5;
    const int ke = rem & 31;                       // even
    const int s = ke >> 3;
    const int j = ke & 7;
    const int korig = ktile * 32 + ((s ^ (col & 3)) << 3) + j;
    const float f0 = J.src[(size_t)col * J.K + korig];
    const float f1 = J.src[(size_t)col * J.K + korig + 1];
    ((unsigned int*)J.dst)[u] = packbf(f0, f1);
  }
}

// ---------------- mean aggregation, bf16 in/out, f32 accum -----------------
__global__ __launch_bounds__(256)
void k_agg128(const unsigned short* __restrict__ h, const int* __restrict__ row_off,
              const int* __restrict__ esrc, const float* __restrict__ deg_inv,
              unsigned short* __restrict__ agg, int N) {
  const int node = blockIdx.x * 4 + (threadIdx.x >> 6);
  if (node >= N) return;
  const int lane = threadIdx.x & 63;
  const int s0 = row_off[node], s1 = row_off[node + 1];
  const unsigned int* hp = (const unsigned int*)h;
  float al = 0.f, ah = 0.f;
  int i = s0;
  for (; i + 4 <= s1; i += 4) {
    const unsigned int u0 = hp[(size_t)esrc[i] * 64 + lane];
    const unsigned int u1 = hp[(size_t)esrc[i + 1] * 64 + lane];
    const unsigned int u2 = hp[(size_t)esrc[i + 2] * 64 + lane];
    const unsigned int u3 = hp[(size_t)esrc[i + 3] * 64 + lane];
    al += lo16(u0) + lo16(u1) + lo16(u2) + lo16(u3);
    ah += hi16(u0) + hi16(u1) + hi16(u2) + hi16(u3);
  }
  for (; i < s1; ++i) {
    const unsigned int u = hp[(size_t)esrc[i] * 64 + lane];
    al += lo16(u); ah += hi16(u);
  }
  const float di = deg_inv[node];
  ((unsigned int*)agg)[(size_t)node * 64 + lane] = packbf(al * di, ah * di);
}

__global__ __launch_bounds__(256)
void k_agg256(const unsigned short* __restrict__ h, const int* __restrict__ row_off,
              const int* __restrict__ esrc, const float* __restrict__ deg_inv,
              unsigned short* __restrict__ agg, int N) {
  const int node = blockIdx.x * 4 + (threadIdx.x >> 6);
  if (node >= N) return;
  const int lane = threadIdx.x & 63;
  const int s0 = row_off[node], s1 = row_off[node + 1];
  const unsigned int* hp = (const unsigned int*)h;
  float al = 0.f, ah = 0.f, bl_ = 0.f, bh = 0.f;
  int i = s0;
  for (; i + 2 <= s1; i += 2) {
    const size_t b0 = (size_t)esrc[i] * 128;
    const size_t b1 = (size_t)esrc[i + 1] * 128;
    const unsigned int u0 = hp[b0 + lane];
    const unsigned int u1 = hp[b0 + 64 + lane];
    const unsigned int u2 = hp[b1 + lane];
    const unsigned int u3 = hp[b1 + 64 + lane];
    al += lo16(u0) + lo16(u2); ah += hi16(u0) + hi16(u2);
    bl_ += lo16(u1) + lo16(u3); bh += hi16(u1) + hi16(u3);
  }
  if (i < s1) {
    const size_t b0 = (size_t)esrc[i] * 128;
    const unsigned int u0 = hp[b0 + lane];
    const unsigned int u1 = hp[b0 + 64 + lane];
    al += lo16(u0); ah += hi16(u0);
    bl_ += lo16(u1); bh += hi16(u1);
  }
  const float di = deg_inv[node];
  unsigned int* ap = (unsigned int*)agg;
  ap[(size_t)node * 128 + lane] = packbf(al * di, ah * di);
  ap[(size_t)node * 128 + 64 + lane] = packbf(bl_ * di, bh * di);
}

__global__ __launch_bounds__(256)
void k_agg64(const unsigned short* __restrict__ h, const int* __restrict__ row_off,
             const int* __restrict__ esrc, const float* __restrict__ deg_inv,
             unsigned short* __restrict__ agg, int N) {
  const int node = blockIdx.x * 4 + (threadIdx.x >> 6);
  if (node >= N) return;
  const int lane = threadIdx.x & 63;
  const int half = lane >> 5, c = lane & 31;
  const int s0 = row_off[node], s1 = row_off[node + 1];
  const unsigned int* hp = (const unsigned int*)h;
  float al = 0.f, ah = 0.f;
  int i = s0 + half;
  for (; i + 2 < s1; i += 4) {
    const unsigned int u0 = hp[(size_t)esrc[i] * 32 + c];
    const unsigned int u1 = hp[(size_t)esrc[i + 2] * 32 + c];
    al += lo16(u0) + lo16(u1);
    ah += hi16(u0) + hi16(u1);
  }
  if (i < s1) {
    const unsigned int u = hp[(size_t)esrc[i] * 32 + c];
    al += lo16(u); ah += hi16(u);
  }
  al += __shfl_xor(al, 32);
  ah += __shfl_xor(ah, 32);
  if (half == 0) {
    const float di = deg_inv[node];
    ((unsigned int*)agg)[(size_t)node * 32 + c] = packbf(al * di, ah * di);
  }
}

// ---------------- fused SAGE GEMM: C = relu(A0@B0p^T + A1@B1p^T + bias) ----
// Block: 128 rows x BN=WC*64 cols; 2 x WC waves; MFMA 32x32x16 (wave 64x64).
// LDS double buffer: [A 128x32 (8KB) | B BNx32 (BN*64B)] x 2.
// A: row-major global, source-swizzled staging. B: pre-packed+swizzled.
template <int WC>
__global__ __launch_bounds__(WC * 128)
void k_sage_gemm(const unsigned short* __restrict__ A0, const unsigned short* __restrict__ B0,
                 const unsigned short* __restrict__ A1, const unsigned short* __restrict__ B1,
                 const float* __restrict__ bias, unsigned short* __restrict__ C,
                 int Nn, int K, int O) {
  constexpr int BN = WC * 64;
  constexpr int T = WC * 128;
  constexpr int LPT = (512 + WC * 256) / T;   // 16B chunks per thread per tile
  constexpr int LDSBUF = 8192 + BN * 64;
  __shared__ char lds[2 * LDSBUF];

  const int tid = threadIdx.x;
  const int w = tid >> 6, lane = tid & 63;
  const int wr = w / WC, wc = w % WC;
  const int fr = lane & 31, fq = lane >> 5;
  const int row0 = blockIdx.x * 128 + wr * 64;
  const int colb = blockIdx.y * BN;

  const int KT0 = K / 32;
  const int NT = 2 * KT0;

  f32x16 acc[2][2];
#pragma unroll
  for (int m = 0; m < 2; ++m)
#pragma unroll
    for (int cn = 0; cn < 2; ++cn)
#pragma unroll
      for (int r = 0; r < 16; ++r) acc[m][cn][r] = 0.f;

  auto stage = [&](int buf, int t) {
    const int ph = (t >= KT0) ? 1 : 0;
    const unsigned short* Ab = ph ? A1 : A0;
    const unsigned short* Bb = ph ? B1 : B0;
    const int ktl = t - ph * KT0;
    char* lb = lds + buf * LDSBUF;
#pragma unroll
    for (int i = 0; i < LPT; ++i) {
      const int ch = tid + i * T;
      if (ch < 512) {
        const int ar = ch >> 2, ac = ch & 3;
        int g = blockIdx.x * 128 + ar;
        if (g >= Nn) g = Nn - 1;
        gl_lds16(Ab + (size_t)g * K + ktl * 32 + ((ac ^ (ar & 3)) << 3), lb + ch * 16);
      } else {
        const int cb = ch - 512;
        gl_lds16(Bb + ((size_t)ktl * O + colb) * 32 + cb * 8, lb + 8192 + cb * 16);
      }
    }
  };

  stage(0, 0);
#pragma unroll 1
  for (int t = 0; t < NT; ++t) {
    asm volatile("s_waitcnt vmcnt(0)" ::: "memory");
    __syncthreads();
    if (t + 1 < NT) stage((t + 1) & 1, t + 1);
    const char* lb = lds + (t & 1) * LDSBUF;
#pragma unroll
    for (int k16i = 0; k16i < 2; ++k16i) {
      bf16x8 af[2], bg[2];
#pragma unroll
      for (int m = 0; m < 2; ++m) {
        const int rl = wr * 64 + m * 32 + fr;
        af[m] = *(const bf16x8*)(lb + rl * 64 + (((k16i * 2 + fq) ^ (rl & 3)) << 4));
      }
#pragma unroll
      for (int cn = 0; cn < 2; ++cn) {
        const int cl = wc * 64 + cn * 32 + fr;
        bg[cn] = *(const bf16x8*)(lb + 8192 + cl * 64 + (((k16i * 2 + fq) ^ (cl & 3)) << 4));
      }
#pragma unroll
      for (int m = 0; m < 2; ++m)
#pragma unroll
        for (int cn = 0; cn < 2; ++cn)
          acc[m][cn] = __builtin_amdgcn_mfma_f32_32x32x16_bf16(af[m], bg[cn], acc[m][cn], 0, 0, 0);
    }
  }

  // epilogue. C/D map: col = lane&31, row = (reg&3) + 8*(reg>>2) + 4*(lane>>5).
#pragma unroll
  for (int cn = 0; cn < 2; ++cn) {
    const int col = colb + wc * 64 + cn * 32 + fr;
    const float bb = bias[col];
#pragma unroll
    for (int m = 0; m < 2; ++m) {
#pragma unroll
      for (int reg = 0; reg < 16; ++reg) {
        const float v = fmaxf(acc[m][cn][reg] + bb, 0.f);
        const float nb = __shfl_xor(v, 1);
        const int row = row0 + m * 32 + (reg & 3) + 8 * (reg >> 2) + 4 * fq;
        if (!(lane & 1) && row < Nn) {
          *(unsigned int*)(C + (size_t)row * O + col) = packbf(v, nb);
        }
      }
    }
  }
}

// ---------------- head: logits(512->4) + softmax, one wave per node --------
__global__ __launch_bounds__(64)
void k_out_softmax(const unsigned short* __restrict__ h, const float* __restrict__ W4,
                   const float* __restrict__ b, float* __restrict__ out) {
  const int n = blockIdx.x;
  const int lane = threadIdx.x;
  const unsigned int* hp = (const unsigned int*)h + (size_t)n * 256;
  float a[4] = {0.f, 0.f, 0.f, 0.f};
#pragma unroll
  for (int it = 0; it < 4; ++it) {
    const unsigned int v = hp[it * 64 + lane];
    const float lo = lo16(v);
    const float hi = hi16(v);
    const int k = (it * 64 + lane) * 2;
#pragma unroll
    for (int c = 0; c < 4; ++c)
      a[c] += lo * W4[c * 512 + k] + hi * W4[c * 512 + k + 1];
  }
#pragma unroll
  for (int off = 32; off > 0; off >>= 1) {
#pragma unroll
    for (int c = 0; c < 4; ++c) a[c] += __shfl_down(a[c], off);
  }
  if (lane == 0) {
    const float l0 = a[0] + b[0], l1 = a[1] + b[1], l2 = a[2] + b[2], l3 = a[3] + b[3];
    const float m = fmaxf(fmaxf(l0, l1), fmaxf(l2, l3));
    const float e0 = expf(l0 - m), e1 = expf(l1 - m), e2 = expf(l2 - m), e3 = expf(l3 - m);
    const float inv = 1.0f / (e0 + e1 + e2 + e3);
    float4 r; r.x = e0 * inv; r.y = e1 * inv; r.z = e2 * inv; r.w = e3 * inv;
    *(float4*)(out + (size_t)n * 4) = r;
  }
}

// ---------------------------------------------------------------------------
extern "C" void kernel_launch(void* const* d_in, const int* in_sizes, int n_in,
                              void* d_out, int out_size, void* d_ws, size_t ws_size,
                              hipStream_t stream) {
  const float* x = (const float*)d_in[0];
  const float* Wl[5] = {(const float*)d_in[1], (const float*)d_in[4], (const float*)d_in[7],
                        (const float*)d_in[10], (const float*)d_in[13]};
  const float* bl[5] = {(const float*)d_in[2], (const float*)d_in[5], (const float*)d_in[8],
                        (const float*)d_in[11], (const float*)d_in[14]};
  const float* Wr[5] = {(const float*)d_in[3], (const float*)d_in[6], (const float*)d_in[9],
                        (const float*)d_in[12], (const float*)d_in[15]};
  const float* Wout = (const float*)d_in[16];
  const float* bout = (const float*)d_in[17];
  const int* eidx = (const int*)d_in[18];

  const int N = in_sizes[0] / 128;
  const int E = in_sizes[18] / 2;
  const int* srcI = eidx;
  const int* dstI = eidx + E;

  const int Kd[5] = {128, 128, 64, 128, 256};
  const int Od[5] = {128, 64, 128, 256, 512};

  // workspace carve-out (256B aligned)
  char* ws = (char*)d_ws;
  size_t p = 0;
  auto alloc = [&](size_t bytes) { size_t r = p; p += (bytes + 255) & ~(size_t)255; return r; };
  int*   deg     = (int*)(ws + alloc((size_t)N * 4));
  int*   row_off = (int*)(ws + alloc((size_t)(N + 1) * 4));
  int*   cursor  = (int*)(ws + alloc((size_t)N * 4));
  float* deg_inv = (float*)(ws + alloc((size_t)N * 4));
  int*   esrc    = (int*)(ws + alloc((size_t)E * 4));
  unsigned short* xb = (unsigned short*)(ws + alloc((size_t)N * 128 * 2));
  unsigned short* wlb[5];
  unsigned short* wrb[5];
  for (int l = 0; l < 5; ++l) {
    wlb[l] = (unsigned short*)(ws + alloc((size_t)Od[l] * Kd[l] * 2));
    wrb[l] = (unsigned short*)(ws + alloc((size_t)Od[l] * Kd[l] * 2));
  }
  unsigned short* bufA = (unsigned short*)(ws + alloc((size_t)N * 512 * 2));
  unsigned short* bufB = (unsigned short*)(ws + alloc((size_t)N * 256 * 2));
  unsigned short* agg  = (unsigned short*)(ws + alloc((size_t)N * 256 * 2));
  (void)ws_size; (void)n_in; (void)out_size;

  // ---- conversions: x plain; weights packed+swizzled ----
  k_conv_x<<<128, 256, 0, stream>>>(x, xb, N * 128 / 4);
  PackJobs jobs;
  for (int l = 0; l < 5; ++l) {
    jobs.j[2 * l]     = {Wl[l], wlb[l], Od[l], Kd[l]};
    jobs.j[2 * l + 1] = {Wr[l], wrb[l], Od[l], Kd[l]};
  }
  k_pack_w<<<dim3(32, 10), 256, 0, stream>>>(jobs);

  // ---- CSR build ----
  k_zero_int<<<idiv_up(N, 256), 256, 0, stream>>>(deg, N);
  k_count_deg<<<idiv_up(E, 256), 256, 0, stream>>>(dstI, deg, E);
  k_scan<<<1, 1024, 0, stream>>>(deg, row_off, cursor, deg_inv, N);
  k_fill_csr<<<idiv_up(E, 256), 256, 0, stream>>>(srcI, dstI, cursor, esrc, E);

  unsigned short* houts[5] = {bufA, bufB, bufA, bufB, bufA};

  const unsigned short* hin = xb;
  for (int l = 0; l < 5; ++l) {
    const int K = Kd[l], O = Od[l];
    // aggregate
    if (K == 64)
      k_agg64<<<idiv_up(N, 4), 256, 0, stream>>>(hin, row_off, esrc, deg_inv, agg, N);
    else if (K == 128)
      k_agg128<<<idiv_up(N, 4), 256, 0, stream>>>(hin, row_off, esrc, deg_inv, agg, N);
    else
      k_agg256<<<idiv_up(N, 4), 256, 0, stream>>>(hin, row_off, esrc, deg_inv, agg, N);

    // fused GEMM + bias + relu
    unsigned short* hout = houts[l];
    const int gx = idiv_up(N, 128);
    switch (l) {
      case 0:  // K=128, O=128: WC=2
        k_sage_gemm<2><<<dim3(gx, 1), 256, 0, stream>>>(agg, wlb[l], hin, wrb[l], bl[l], hout, N, K, O);
        break;
      case 1:  // K=128, O=64: WC=1
        k_sage_gemm<1><<<dim3(gx, 1), 128, 0, stream>>>(agg, wlb[l], hin, wrb[l], bl[l], hout, N, K, O);
        break;
      case 2:  // K=64, O=128: WC=2
        k_sage_gemm<2><<<dim3(gx, 1), 256, 0, stream>>>(agg, wlb[l], hin, wrb[l], bl[l], hout, N, K, O);
        break;
      case 3:  // K=128, O=256: WC=4
        k_sage_gemm<4><<<dim3(gx, 1), 512, 0, stream>>>(agg, wlb[l], hin, wrb[l], bl[l], hout, N, K, O);
        break;
      default: // K=256, O=512: WC=4, col-split x2
        k_sage_gemm<4><<<dim3(gx, 2), 512, 0, stream>>>(agg, wlb[l], hin, wrb[l], bl[l], hout, N, K, O);
        break;
    }
    hin = hout;
  }
  k_out_softmax<<<N, 64, 0, stream>>>(hin, Wout, bout, (float*)d_out);
}

// Round 6
// 511.244 us; speedup vs baseline: 2.4886x; 1.0320x over previous
//
#include <hip/hip_runtime.h>
#include <hip/hip_bf16.h>
#include <cstdint>
#include <cstddef>

// ---------------------------------------------------------------------------
// SAGE GNN forward, bf16 MFMA 32x32x16, LDS-staged GEMM, BK=64.
//  - A tile [128][128B], XOR-swizzle byte^=(row&7)<<4 (stage: inverse-swizzled
//    per-lane global source, linear LDS dest; read: swizzled addr) -> 0 conflicts
//  - B pre-packed chunk-major [kt64][chunk][col][16B]: linear stage, contiguous read
//  - double buffer, vmcnt(0)+barrier per 64-wide K-step
// ---------------------------------------------------------------------------

typedef short bf16x8 __attribute__((ext_vector_type(8)));   // 8 bf16 = 4 VGPRs
typedef float f32x16 __attribute__((ext_vector_type(16)));

static inline int idiv_up(int a, int b) { return (a + b - 1) / b; }

static __device__ __forceinline__ float bf2f(unsigned short u) {
  union { unsigned int i; float f; } v; v.i = ((unsigned int)u) << 16; return v.f;
}
static __device__ __forceinline__ unsigned short f2bf(float f) {
  union { float f; unsigned int i; } v; v.f = f;
  return (unsigned short)((v.i + 0x7FFFu + ((v.i >> 16) & 1u)) >> 16);  // RNE
}
static __device__ __forceinline__ float lo16(unsigned int u) { return bf2f((unsigned short)(u & 0xffffu)); }
static __device__ __forceinline__ float hi16(unsigned int u) { return bf2f((unsigned short)(u >> 16)); }
static __device__ __forceinline__ unsigned int packbf(float a, float b) {
  return (unsigned int)f2bf(a) | ((unsigned int)f2bf(b) << 16);
}

// async global->LDS, 16B per lane. LDS dest: wave-uniform base + lane*16.
static __device__ __forceinline__ void gl_lds16(const void* g, void* l) {
  typedef __attribute__((address_space(3))) unsigned int lds_u32;
  typedef __attribute__((address_space(1))) const unsigned int glb_u32;
  __builtin_amdgcn_global_load_lds((glb_u32*)(uintptr_t)g,
                                   (lds_u32*)(unsigned int)(uintptr_t)l, 16, 0, 0);
}

// ---------------- CSR build ----------------
__global__ void k_zero_int(int* __restrict__ p, int n) {
  int i = blockIdx.x * blockDim.x + threadIdx.x;
  if (i < n) p[i] = 0;
}

__global__ void k_count_deg(const int* __restrict__ dst, int* __restrict__ deg, int E) {
  int e = blockIdx.x * blockDim.x + threadIdx.x;
  if (e < E) atomicAdd(deg + dst[e], 1);
}

// wave-shfl hierarchical scan, 1024 threads, chunked.
__global__ __launch_bounds__(1024)
void k_scan(const int* __restrict__ deg, int* __restrict__ row_off, int* __restrict__ cursor,
            float* __restrict__ deg_inv, int n) {
  __shared__ int wsum[16];
  const int tid = threadIdx.x;
  const int lane = tid & 63, wid = tid >> 6;
  int carry = 0;
  for (int base = 0; base < n; base += 1024) {
    const int i = base + tid;
    const int v = (i < n) ? deg[i] : 0;
    int incl = v;
#pragma unroll
    for (int off = 1; off < 64; off <<= 1) {
      int t = __shfl_up(incl, off);
      if (lane >= off) incl += t;
    }
    if (lane == 63) wsum[wid] = incl;
    __syncthreads();
    if (wid == 0) {
      int wv = (lane < 16) ? wsum[lane] : 0;
#pragma unroll
      for (int off = 1; off < 16; off <<= 1) {
        int t = __shfl_up(wv, off);
        if (lane >= off) wv += t;
      }
      if (lane < 16) wsum[lane] = wv;
    }
    __syncthreads();
    const int woff = (wid > 0) ? wsum[wid - 1] : 0;
    if (i < n) {
      const int ro = carry + woff + incl - v;
      row_off[i] = ro;
      cursor[i] = ro;
      deg_inv[i] = 1.0f / (float)((v > 1) ? v : 1);
    }
    const int tot = wsum[15];
    __syncthreads();
    carry += tot;
  }
  if (tid == 0) row_off[n] = carry;
}

__global__ void k_fill_csr(const int* __restrict__ src, const int* __restrict__ dst,
                           int* __restrict__ cursor, int* __restrict__ esrc, int E) {
  int e = blockIdx.x * blockDim.x + threadIdx.x;
  if (e < E) {
    int d = dst[e];
    int p = atomicAdd(cursor + d, 1);
    esrc[p] = src[e];
  }
}

// ---------------- x: f32 -> bf16 plain conversion --------------------------
__global__ __launch_bounds__(256)
void k_conv_x(const float* __restrict__ src, unsigned short* __restrict__ dst, int n4) {
  for (int i = blockIdx.x * blockDim.x + threadIdx.x; i < n4; i += gridDim.x * blockDim.x) {
    const float4 v = *((const float4*)src + i);
    uint2 o;
    o.x = packbf(v.x, v.y);
    o.y = packbf(v.z, v.w);
    *((uint2*)dst + i) = o;
  }
}

// ---------------- weights: f32 -> bf16 packed chunk-major ------------------
// dst elem index = kt64*(O*64) + chunk*(O*8) + col*8 + j  holds
// src[col][kt64*64 + chunk*8 + j]  (chunk in 0..7)
struct PackJob { const float* src; unsigned short* dst; int O; int K; };
struct PackJobs { PackJob j[10]; };

__global__ __launch_bounds__(256)
void k_pack_w(PackJobs jobs) {
  const PackJob J = jobs.j[blockIdx.y];
  const int total = J.O * J.K / 2;  // u32 outputs
  const int OK64 = J.O * 64;
  for (int u = blockIdx.x * blockDim.x + threadIdx.x; u < total; u += gridDim.x * blockDim.x) {
    const int e = u * 2;
    const int kt = e / OK64;
    const int rem = e - kt * OK64;
    const int chunk = rem / (J.O * 8);
    const int rem2 = rem - chunk * (J.O * 8);
    const int col = rem2 >> 3;
    const int j = rem2 & 7;
    const int korig = kt * 64 + chunk * 8 + j;
    const float f0 = J.src[(size_t)col * J.K + korig];
    const float f1 = J.src[(size_t)col * J.K + korig + 1];
    ((unsigned int*)J.dst)[u] = packbf(f0, f1);
  }
}

// ---------------- mean aggregation, bf16 in/out, f32 accum -----------------
__global__ __launch_bounds__(256)
void k_agg128(const unsigned short* __restrict__ h, const int* __restrict__ row_off,
              const int* __restrict__ esrc, const float* __restrict__ deg_inv,
              unsigned short* __restrict__ agg, int N) {
  const int node = blockIdx.x * 4 + (threadIdx.x >> 6);
  if (node >= N) return;
  const int lane = threadIdx.x & 63;
  const int s0 = row_off[node], s1 = row_off[node + 1];
  const unsigned int* hp = (const unsigned int*)h;
  float al = 0.f, ah = 0.f;
  int i = s0;
  for (; i + 8 <= s1; i += 8) {
    unsigned int u[8];
#pragma unroll
    for (int j = 0; j < 8; ++j) u[j] = hp[(size_t)esrc[i + j] * 64 + lane];
#pragma unroll
    for (int j = 0; j < 8; ++j) { al += lo16(u[j]); ah += hi16(u[j]); }
  }
  for (; i < s1; ++i) {
    const unsigned int u = hp[(size_t)esrc[i] * 64 + lane];
    al += lo16(u); ah += hi16(u);
  }
  const float di = deg_inv[node];
  ((unsigned int*)agg)[(size_t)node * 64 + lane] = packbf(al * di, ah * di);
}

__global__ __launch_bounds__(256)
void k_agg256(const unsigned short* __restrict__ h, const int* __restrict__ row_off,
              const int* __restrict__ esrc, const float* __restrict__ deg_inv,
              unsigned short* __restrict__ agg, int N) {
  const int node = blockIdx.x * 4 + (threadIdx.x >> 6);
  if (node >= N) return;
  const int lane = threadIdx.x & 63;
  const int s0 = row_off[node], s1 = row_off[node + 1];
  const unsigned int* hp = (const unsigned int*)h;
  float al = 0.f, ah = 0.f, bl_ = 0.f, bh = 0.f;
  int i = s0;
  for (; i + 4 <= s1; i += 4) {
    unsigned int u0[4], u1[4];
#pragma unroll
    for (int j = 0; j < 4; ++j) {
      const size_t b = (size_t)esrc[i + j] * 128;
      u0[j] = hp[b + lane];
      u1[j] = hp[b + 64 + lane];
    }
#pragma unroll
    for (int j = 0; j < 4; ++j) {
      al += lo16(u0[j]); ah += hi16(u0[j]);
      bl_ += lo16(u1[j]); bh += hi16(u1[j]);
    }
  }
  for (; i < s1; ++i) {
    const size_t b = (size_t)esrc[i] * 128;
    const unsigned int u0 = hp[b + lane];
    const unsigned int u1 = hp[b + 64 + lane];
    al += lo16(u0); ah += hi16(u0);
    bl_ += lo16(u1); bh += hi16(u1);
  }
  const float di = deg_inv[node];
  unsigned int* ap = (unsigned int*)agg;
  ap[(size_t)node * 128 + lane] = packbf(al * di, ah * di);
  ap[(size_t)node * 128 + 64 + lane] = packbf(bl_ * di, bh * di);
}

__global__ __launch_bounds__(256)
void k_agg64(const unsigned short* __restrict__ h, const int* __restrict__ row_off,
             const int* __restrict__ esrc, const float* __restrict__ deg_inv,
             unsigned short* __restrict__ agg, int N) {
  const int node = blockIdx.x * 4 + (threadIdx.x >> 6);
  if (node >= N) return;
  const int lane = threadIdx.x & 63;
  const int half = lane >> 5, c = lane & 31;
  const int s0 = row_off[node], s1 = row_off[node + 1];
  const unsigned int* hp = (const unsigned int*)h;
  float al = 0.f, ah = 0.f;
  int i = s0 + half;
  for (; i + 6 < s1; i += 8) {  // 4 edges per half per iter
    const unsigned int u0 = hp[(size_t)esrc[i] * 32 + c];
    const unsigned int u1 = hp[(size_t)esrc[i + 2] * 32 + c];
    const unsigned int u2 = hp[(size_t)esrc[i + 4] * 32 + c];
    const unsigned int u3 = hp[(size_t)esrc[i + 6] * 32 + c];
    al += lo16(u0) + lo16(u1) + lo16(u2) + lo16(u3);
    ah += hi16(u0) + hi16(u1) + hi16(u2) + hi16(u3);
  }
  for (; i < s1; i += 2) {
    const unsigned int u = hp[(size_t)esrc[i] * 32 + c];
    al += lo16(u); ah += hi16(u);
  }
  al += __shfl_xor(al, 32);
  ah += __shfl_xor(ah, 32);
  if (half == 0) {
    const float di = deg_inv[node];
    ((unsigned int*)agg)[(size_t)node * 32 + c] = packbf(al * di, ah * di);
  }
}

// ---------------- fused SAGE GEMM: C = relu(A0@B0p^T + A1@B1p^T + bias) ----
// Block: 128 rows x BN=WC*64 cols; 2 x WC waves; MFMA 32x32x16; BK=64.
// LDS/buf: A[128][128B] swizzled (16KB) + B[8][BN][16B] chunk-major (BN*128B).
template <int WC>
__global__ __launch_bounds__(WC * 128)
void k_sage_gemm(const unsigned short* __restrict__ A0, const unsigned short* __restrict__ B0,
                 const unsigned short* __restrict__ A1, const unsigned short* __restrict__ B1,
                 const float* __restrict__ bias, unsigned short* __restrict__ C,
                 int Nn, int K, int O) {
  constexpr int BN = WC * 64;
  constexpr int T = WC * 128;
  constexpr int ACH = 1024;            // A 16B-chunks per tile (128 rows x 8)
  constexpr int BCH = BN * 8;          // B 16B-chunks per tile
  constexpr int LPT = (ACH + BCH) / T; // chunks per thread per stage
  constexpr int BSH = (WC == 1) ? 6 : ((WC == 2) ? 7 : 8);  // log2(BN)
  constexpr int LDSBUF = 16384 + BN * 128;
  __shared__ char lds[2 * LDSBUF];

  const int tid = threadIdx.x;
  const int w = tid >> 6, lane = tid & 63;
  const int wr = w / WC, wc = w % WC;
  const int fr = lane & 31, fq = lane >> 5;
  const int row0 = blockIdx.x * 128 + wr * 64;
  const int colb = blockIdx.y * BN;

  const int KT0 = K >> 6;        // 64-wide tiles per phase
  const int NT = 2 * KT0;

  f32x16 acc[2][2];
#pragma unroll
  for (int m = 0; m < 2; ++m)
#pragma unroll
    for (int cn = 0; cn < 2; ++cn)
#pragma unroll
      for (int r = 0; r < 16; ++r) acc[m][cn][r] = 0.f;

  auto stage = [&](int buf, int t) {
    const int ph = (t >= KT0) ? 1 : 0;
    const unsigned short* Ab = ph ? A1 : A0;
    const unsigned short* Bb = ph ? B1 : B0;
    const int ktl = t - ph * KT0;
    char* lb = lds + buf * LDSBUF;
#pragma unroll
    for (int i = 0; i < LPT; ++i) {
      const int ch = tid + i * T;
      if (ch < ACH) {
        const int ar = ch >> 3, s = ch & 7;         // LDS row, slot
        int g = blockIdx.x * 128 + ar;
        if (g >= Nn) g = Nn - 1;
        // inverse-swizzled global source; linear LDS dest
        gl_lds16(Ab + (size_t)g * K + ktl * 64 + ((s ^ (ar & 7)) << 3), lb + ch * 16);
      } else {
        const int cb = ch - ACH;
        const int chunk = cb >> BSH, colrel = cb & (BN - 1);
        gl_lds16(Bb + (size_t)ktl * O * 64 + chunk * O * 8 + (colb + colrel) * 8,
                 lb + 16384 + cb * 16);
      }
    }
  };

  stage(0, 0);
#pragma unroll 1
  for (int t = 0; t < NT; ++t) {
    asm volatile("s_waitcnt vmcnt(0)" ::: "memory");
    __syncthreads();
    if (t + 1 < NT) stage((t + 1) & 1, t + 1);
    const char* lb = lds + (t & 1) * LDSBUF;
#pragma unroll
    for (int k16i = 0; k16i < 4; ++k16i) {
      const int c = k16i * 2 + fq;                  // chunk 0..7
      bf16x8 af[2], bg[2];
#pragma unroll
      for (int m = 0; m < 2; ++m) {
        const int rl = wr * 64 + m * 32 + fr;
        af[m] = *(const bf16x8*)(lb + rl * 128 + ((c ^ (rl & 7)) << 4));
      }
#pragma unroll
      for (int cn = 0; cn < 2; ++cn) {
        const int colrel = wc * 64 + cn * 32 + fr;
        bg[cn] = *(const bf16x8*)(lb + 16384 + c * (BN * 16) + colrel * 16);
      }
#pragma unroll
      for (int m = 0; m < 2; ++m)
#pragma unroll
        for (int cn = 0; cn < 2; ++cn)
          acc[m][cn] = __builtin_amdgcn_mfma_f32_32x32x16_bf16(af[m], bg[cn], acc[m][cn], 0, 0, 0);
    }
  }

  // epilogue. C/D map: col = lane&31, row = (reg&3) + 8*(reg>>2) + 4*(lane>>5).
#pragma unroll
  for (int cn = 0; cn < 2; ++cn) {
    const int col = colb + wc * 64 + cn * 32 + fr;
    const float bb = bias[col];
#pragma unroll
    for (int m = 0; m < 2; ++m) {
#pragma unroll
      for (int reg = 0; reg < 16; ++reg) {
        const float v = fmaxf(acc[m][cn][reg] + bb, 0.f);
        const float nb = __shfl_xor(v, 1);
        const int row = row0 + m * 32 + (reg & 3) + 8 * (reg >> 2) + 4 * fq;
        if (!(lane & 1) && row < Nn) {
          *(unsigned int*)(C + (size_t)row * O + col) = packbf(v, nb);
        }
      }
    }
  }
}

// ---------------- head: logits(512->4) + softmax, one wave per node --------
__global__ __launch_bounds__(64)
void k_out_softmax(const unsigned short* __restrict__ h, const float* __restrict__ W4,
                   const float* __restrict__ b, float* __restrict__ out) {
  const int n = blockIdx.x;
  const int lane = threadIdx.x;
  const unsigned int* hp = (const unsigned int*)h + (size_t)n * 256;
  float a[4] = {0.f, 0.f, 0.f, 0.f};
#pragma unroll
  for (int it = 0; it < 4; ++it) {
    const unsigned int v = hp[it * 64 + lane];
    const float lo = lo16(v);
    const float hi = hi16(v);
    const int k = (it * 64 + lane) * 2;
#pragma unroll
    for (int c = 0; c < 4; ++c)
      a[c] += lo * W4[c * 512 + k] + hi * W4[c * 512 + k + 1];
  }
#pragma unroll
  for (int off = 32; off > 0; off >>= 1) {
#pragma unroll
    for (int c = 0; c < 4; ++c) a[c] += __shfl_down(a[c], off);
  }
  if (lane == 0) {
    const float l0 = a[0] + b[0], l1 = a[1] + b[1], l2 = a[2] + b[2], l3 = a[3] + b[3];
    const float m = fmaxf(fmaxf(l0, l1), fmaxf(l2, l3));
    const float e0 = expf(l0 - m), e1 = expf(l1 - m), e2 = expf(l2 - m), e3 = expf(l3 - m);
    const float inv = 1.0f / (e0 + e1 + e2 + e3);
    float4 r; r.x = e0 * inv; r.y = e1 * inv; r.z = e2 * inv; r.w = e3 * inv;
    *(float4*)(out + (size_t)n * 4) = r;
  }
}

// ---------------------------------------------------------------------------
extern "C" void kernel_launch(void* const* d_in, const int* in_sizes, int n_in,
                              void* d_out, int out_size, void* d_ws, size_t ws_size,
                              hipStream_t stream) {
  const float* x = (const float*)d_in[0];
  const float* Wl[5] = {(const float*)d_in[1], (const float*)d_in[4], (const float*)d_in[7],
                        (const float*)d_in[10], (const float*)d_in[13]};
  const float* bl[5] = {(const float*)d_in[2], (const float*)d_in[5], (const float*)d_in[8],
                        (const float*)d_in[11], (const float*)d_in[14]};
  const float* Wr[5] = {(const float*)d_in[3], (const float*)d_in[6], (const float*)d_in[9],
                        (const float*)d_in[12], (const float*)d_in[15]};
  const float* Wout = (const float*)d_in[16];
  const float* bout = (const float*)d_in[17];
  const int* eidx = (const int*)d_in[18];

  const int N = in_sizes[0] / 128;
  const int E = in_sizes[18] / 2;
  const int* srcI = eidx;
  const int* dstI = eidx + E;

  const int Kd[5] = {128, 128, 64, 128, 256};
  const int Od[5] = {128, 64, 128, 256, 512};

  // workspace carve-out (256B aligned)
  char* ws = (char*)d_ws;
  size_t p = 0;
  auto alloc = [&](size_t bytes) { size_t r = p; p += (bytes + 255) & ~(size_t)255; return r; };
  int*   deg     = (int*)(ws + alloc((size_t)N * 4));
  int*   row_off = (int*)(ws + alloc((size_t)(N + 1) * 4));
  int*   cursor  = (int*)(ws + alloc((size_t)N * 4));
  float* deg_inv = (float*)(ws + alloc((size_t)N * 4));
  int*   esrc    = (int*)(ws + alloc((size_t)E * 4));
  unsigned short* xb = (unsigned short*)(ws + alloc((size_t)N * 128 * 2));
  unsigned short* wlb[5];
  unsigned short* wrb[5];
  for (int l = 0; l < 5; ++l) {
    wlb[l] = (unsigned short*)(ws + alloc((size_t)Od[l] * Kd[l] * 2));
    wrb[l] = (unsigned short*)(ws + alloc((size_t)Od[l] * Kd[l] * 2));
  }
  unsigned short* bufA = (unsigned short*)(ws + alloc((size_t)N * 512 * 2));
  unsigned short* bufB = (unsigned short*)(ws + alloc((size_t)N * 256 * 2));
  unsigned short* agg  = (unsigned short*)(ws + alloc((size_t)N * 256 * 2));
  (void)ws_size; (void)n_in; (void)out_size;

  // ---- conversions: x plain; weights packed chunk-major ----
  k_conv_x<<<128, 256, 0, stream>>>(x, xb, N * 128 / 4);
  PackJobs jobs;
  for (int l = 0; l < 5; ++l) {
    jobs.j[2 * l]     = {Wl[l], wlb[l], Od[l], Kd[l]};
    jobs.j[2 * l + 1] = {Wr[l], wrb[l], Od[l], Kd[l]};
  }
  k_pack_w<<<dim3(32, 10), 256, 0, stream>>>(jobs);

  // ---- CSR build ----
  k_zero_int<<<idiv_up(N, 256), 256, 0, stream>>>(deg, N);
  k_count_deg<<<idiv_up(E, 256), 256, 0, stream>>>(dstI, deg, E);
  k_scan<<<1, 1024, 0, stream>>>(deg, row_off, cursor, deg_inv, N);
  k_fill_csr<<<idiv_up(E, 256), 256, 0, stream>>>(srcI, dstI, cursor, esrc, E);

  unsigned short* houts[5] = {bufA, bufB, bufA, bufB, bufA};

  const unsigned short* hin = xb;
  for (int l = 0; l < 5; ++l) {
    const int K = Kd[l], O = Od[l];
    // aggregate
    if (K == 64)
      k_agg64<<<idiv_up(N, 4), 256, 0, stream>>>(hin, row_off, esrc, deg_inv, agg, N);
    else if (K == 128)
      k_agg128<<<idiv_up(N, 4), 256, 0, stream>>>(hin, row_off, esrc, deg_inv, agg, N);
    else
      k_agg256<<<idiv_up(N, 4), 256, 0, stream>>>(hin, row_off, esrc, deg_inv, agg, N);

    // fused GEMM + bias + relu
    unsigned short* hout = houts[l];
    const int gx = idiv_up(N, 128);
    switch (l) {
      case 0:  // K=128, O=128: WC=2
        k_sage_gemm<2><<<dim3(gx, 1), 256, 0, stream>>>(agg, wlb[l], hin, wrb[l], bl[l], hout, N, K, O);
        break;
      case 1:  // K=128, O=64: WC=1
        k_sage_gemm<1><<<dim3(gx, 1), 128, 0, stream>>>(agg, wlb[l], hin, wrb[l], bl[l], hout, N, K, O);
        break;
      case 2:  // K=64, O=128: WC=2
        k_sage_gemm<2><<<dim3(gx, 1), 256, 0, stream>>>(agg, wlb[l], hin, wrb[l], bl[l], hout, N, K, O);
        break;
      case 3:  // K=128, O=256: WC=2, col-split x2
        k_sage_gemm<2><<<dim3(gx, 2), 256, 0, stream>>>(agg, wlb[l], hin, wrb[l], bl[l], hout, N, K, O);
        break;
      default: // K=256, O=512: WC=2, col-split x4
        k_sage_gemm<2><<<dim3(gx, 4), 256, 0, stream>>>(agg, wlb[l], hin, wrb[l], bl[l], hout, N, K, O);
        break;
    }
    hin = hout;
  }
  k_out_softmax<<<N, 64, 0, stream>>>(hin, Wout, bout, (float*)d_out);
}